// Round 9
// baseline (5248.170 us; speedup 1.0000x reference)
//
#include <hip/hip_runtime.h>
#include <hip/hip_bf16.h>
#include <math.h>

// CrossCBR R9: edge-parallel LDS-accumulate SpMM over bucketed (row,col) pairs.
// No CSR (scan/csrfill/col deleted); one global padded row space for all 3
// graphs; UI+UB propagate merged per layer; F1/F2 kept only as bf16 mirrors.
// 16 dispatches total (was ~45).
static constexpr int NUc  = 50000;
static constexpr int NBUc = 20000;
static constexpr int NIc  = 100000;
static constexpr int NILc = 150000;           // UI graph nodes
static constexpr int NBLc = 70000;            // UB graph nodes
// global padded rows: UI [0,150016), UB [150016,220032), BI [220032,240128)
static constexpr int GUB0   = 150016;         // = 1172*128
static constexpr int GBI0   = 220032;         // = 1719*128
static constexpr int BK_UB0 = 1172;
static constexpr int BK_BI0 = 1719;
static constexpr int NBK    = 1876;           // ceil(240032/128)
static constexpr int GTOT   = NBK * 128;      // 240128

__device__ __forceinline__ float wredsum(float v) {
  #pragma unroll
  for (int m = 32; m >= 1; m >>= 1) v += __shfl_xor(v, m, 64);
  return v;
}
__device__ __forceinline__ float bf2f(unsigned short h) {
  return __uint_as_float(((unsigned int)h) << 16);
}
__device__ __forceinline__ unsigned short f2bf(float f) {  // RNE
  unsigned int u = __float_as_uint(f);
  return (unsigned short)((u + 0x7FFFu + ((u >> 16) & 1u)) >> 16);
}

// ---------------- bucket counts (all 3 graphs, one launch) ----------------
__global__ void k_bcount_all(const int* __restrict__ ui_u, const int* __restrict__ ui_i,
                             const int* __restrict__ ub_u, const int* __restrict__ ub_b,
                             const int* __restrict__ bi_b,
                             int E_ui, int E_ub, int E_bi, int* __restrict__ bCnt) {
  __shared__ int hist[NBK];
  for (int i = threadIdx.x; i < NBK; i += 256) hist[i] = 0;
  __syncthreads();
  int b = blockIdx.x;
  if (b < 512) {
    int chunk = (E_ui + 511) / 512, c0 = b * chunk, c1 = min(E_ui, c0 + chunk);
    for (int e = c0 + (int)threadIdx.x; e < c1; e += 256) {
      atomicAdd(&hist[ui_u[e] >> 7], 1);
      atomicAdd(&hist[(ui_i[e] + NUc) >> 7], 1);
    }
  } else if (b < 768) {
    int lb = b - 512, chunk = (E_ub + 255) / 256, c0 = lb * chunk, c1 = min(E_ub, c0 + chunk);
    for (int e = c0 + (int)threadIdx.x; e < c1; e += 256) {
      atomicAdd(&hist[(GUB0 + ub_u[e]) >> 7], 1);
      atomicAdd(&hist[(GUB0 + NUc + ub_b[e]) >> 7], 1);
    }
  } else {
    int lb = b - 768, chunk = (E_bi + 255) / 256, c0 = lb * chunk, c1 = min(E_bi, c0 + chunk);
    for (int e = c0 + (int)threadIdx.x; e < c1; e += 256)
      atomicAdd(&hist[(GBI0 + bi_b[e]) >> 7], 1);
  }
  __syncthreads();
  for (int i = threadIdx.x; i < NBK; i += 256)
    if (hist[i]) atomicAdd(&bCnt[i], hist[i]);
}

// exclusive scan of bCnt[0..n) (n<=2048), 1 block x 512
__global__ void k_scan2048(const int* __restrict__ in, int n,
                           int* __restrict__ outBase, int* __restrict__ outCur) {
  __shared__ int sh[512];
  int t = threadIdx.x, i0 = 4 * t;
  int v0 = (i0 < n) ? in[i0] : 0;
  int v1 = (i0 + 1 < n) ? in[i0 + 1] : 0;
  int v2 = (i0 + 2 < n) ? in[i0 + 2] : 0;
  int v3 = (i0 + 3 < n) ? in[i0 + 3] : 0;
  int ts = v0 + v1 + v2 + v3;
  sh[t] = ts;
  __syncthreads();
  for (int o = 1; o < 512; o <<= 1) {
    int x = (t >= o) ? sh[t - o] : 0;
    __syncthreads();
    sh[t] += x;
    __syncthreads();
  }
  int ex = sh[t] - ts;
  if (i0 < n)     { outBase[i0] = ex;                outCur[i0] = ex; }
  if (i0 + 1 < n) { outBase[i0 + 1] = ex + v0;       outCur[i0 + 1] = ex + v0; }
  if (i0 + 2 < n) { outBase[i0 + 2] = ex + v0 + v1;  outCur[i0 + 2] = ex + v0 + v1; }
  if (i0 + 3 < n) { outBase[i0 + 3] = ex + v0 + v1 + v2; outCur[i0 + 3] = ex + v0 + v1 + v2; }
  if (t == 511) outBase[n] = sh[511];
}

// ---------------- bin all edges -> bucket-sorted (row,col) pairs ----------------
__global__ void k_bin_all(const int* __restrict__ ui_u, const int* __restrict__ ui_i,
                          const int* __restrict__ ub_u, const int* __restrict__ ub_b,
                          const int* __restrict__ bi_b, const int* __restrict__ bi_i,
                          int E_ui, int E_ub, int E_bi,
                          int* __restrict__ bCur, int2* __restrict__ binned) {
  __shared__ int hist[NBK];
  __shared__ int base[NBK];
  for (int i = threadIdx.x; i < NBK; i += 256) hist[i] = 0;
  __syncthreads();
  int b = blockIdx.x;
  int c0, c1, seg;
  if (b < 512)      { seg = 0; int ch = (E_ui + 511) / 512; c0 = b * ch; c1 = min(E_ui, c0 + ch); }
  else if (b < 768) { seg = 1; int ch = (E_ub + 255) / 256; c0 = (b - 512) * ch; c1 = min(E_ub, c0 + ch); }
  else              { seg = 2; int ch = (E_bi + 255) / 256; c0 = (b - 768) * ch; c1 = min(E_bi, c0 + ch); }
  // pass 1: count
  for (int e = c0 + (int)threadIdx.x; e < c1; e += 256) {
    if (seg == 0) {
      atomicAdd(&hist[ui_u[e] >> 7], 1);
      atomicAdd(&hist[(ui_i[e] + NUc) >> 7], 1);
    } else if (seg == 1) {
      atomicAdd(&hist[(GUB0 + ub_u[e]) >> 7], 1);
      atomicAdd(&hist[(GUB0 + NUc + ub_b[e]) >> 7], 1);
    } else {
      atomicAdd(&hist[(GBI0 + bi_b[e]) >> 7], 1);
    }
  }
  __syncthreads();
  // reserve
  for (int i = threadIdx.x; i < NBK; i += 256) {
    int h = hist[i];
    base[i] = h ? atomicAdd(&bCur[i], h) : 0;
    hist[i] = 0;
  }
  __syncthreads();
  // pass 2: emit
  for (int e = c0 + (int)threadIdx.x; e < c1; e += 256) {
    if (seg == 0) {
      int u = ui_u[e], x = ui_i[e] + NUc;     // rows global == local (base 0)
      int b1 = u >> 7; binned[base[b1] + atomicAdd(&hist[b1], 1)] = make_int2(u, x);
      int b2 = x >> 7; binned[base[b2] + atomicAdd(&hist[b2], 1)] = make_int2(x, u);
    } else if (seg == 1) {
      int ul = ub_u[e], bl = NUc + ub_b[e];
      int r1 = GUB0 + ul, r2 = GUB0 + bl;
      int b1 = r1 >> 7; binned[base[b1] + atomicAdd(&hist[b1], 1)] = make_int2(r1, bl);
      int b2 = r2 >> 7; binned[base[b2] + atomicAdd(&hist[b2], 1)] = make_int2(r2, ul);
    } else {
      int r = GBI0 + bi_b[e];
      int b1 = r >> 7; binned[base[b1] + atomicAdd(&hist[b1], 1)] = make_int2(r, bi_i[e]);
    }
  }
}

// per-row degree from binned (covers all padded rows; no memset needed)
__global__ void k_rowhist_all(const int2* __restrict__ binned, const int* __restrict__ bBase,
                              int* __restrict__ cnt) {
  __shared__ int hist[128];
  int bk = blockIdx.x, rowbase = bk << 7;
  int s = bBase[bk], e = bBase[bk + 1];
  if (threadIdx.x < 128) hist[threadIdx.x] = 0;
  __syncthreads();
  for (int i = s + (int)threadIdx.x; i < e; i += 256)
    atomicAdd(&hist[binned[i].x & 127], 1);
  __syncthreads();
  if (threadIdx.x < 128) cnt[rowbase + (int)threadIdx.x] = hist[threadIdx.x];
}

// X[g] = f2bf(feat[g] * dinv[g]) over global rows [0, GBI0)
__global__ void k_prescale_all(const int* __restrict__ cnt, const float* __restrict__ userF,
                               const float* __restrict__ bundF, const float* __restrict__ itemF,
                               unsigned short* __restrict__ X) {
  long idx = (long)blockIdx.x * 256 + threadIdx.x;
  if (idx >= (long)GBI0 * 64) return;
  int g = (int)(idx >> 6), d = (int)(idx & 63);
  float v = 0.0f;
  if (g < NILc) v = (g < NUc) ? userF[(long)g * 64 + d] : itemF[(long)(g - NUc) * 64 + d];
  else if (g >= GUB0 && g < GUB0 + NBLc) {
    int l = g - GUB0;
    v = (l < NUc) ? userF[(long)l * 64 + d] : bundF[(long)(l - NUc) * 64 + d];
  }
  float dinv = 1.0f / (sqrtf((float)cnt[g]) + 1e-8f);
  X[idx] = f2bf(v * dinv);
}

// ---------------- edge-parallel LDS-accumulate SpMM ----------------
// block = bucket; sAcc[128][65] skewed; quarter q handles edge base+q, lane p
// loads uint2 (4 dims). Epilogue: outB[g]=f2bf(val*(mulDinv?dinv:1)), INV[g].
__global__ void k_spmm_lds(const int2* __restrict__ binned, const int* __restrict__ bBase,
                           const int* __restrict__ cnt, const unsigned short* __restrict__ X,
                           unsigned short* __restrict__ outB, float* __restrict__ outInv,
                           float scale, int mulDinv) {
  __shared__ float sAcc[128 * 65];
  int bk = blockIdx.x;
  int rowbase = bk << 7;
  int xbase = (bk < BK_UB0) ? 0 : GUB0;
  int s = bBase[bk], e = bBase[bk + 1];
  for (int i = threadIdx.x; i < 128 * 65; i += 256) sAcc[i] = 0.0f;
  __syncthreads();
  int lane = threadIdx.x & 63, w = threadIdx.x >> 6;
  int q = lane >> 4, p = lane & 15;
  for (int base = s + (w << 2); base < e; base += 16) {
    int eidx = base + q;
    if (eidx < e) {
      int2 rc = binned[eidx];
      uint2 v = ((const uint2*)(X + (size_t)(xbase + rc.y) * 64))[p];
      float* dst = sAcc + (rc.x & 127) * 65 + p * 4;
      atomicAdd(dst + 0, __uint_as_float(v.x << 16));
      atomicAdd(dst + 1, __uint_as_float(v.x & 0xFFFF0000u));
      atomicAdd(dst + 2, __uint_as_float(v.y << 16));
      atomicAdd(dst + 3, __uint_as_float(v.y & 0xFFFF0000u));
    }
  }
  __syncthreads();
  for (int r = w; r < 128; r += 4) {
    int g = rowbase + r;
    float dinv = 1.0f / (sqrtf((float)cnt[g]) + 1e-8f);
    float val = sAcc[r * 65 + lane] * (dinv * scale);
    float ss = wredsum(val * val);
    outB[(size_t)g * 64 + lane] = f2bf(mulDinv ? val * dinv : val);
    if (lane == 0) outInv[g] = 1.0f / fmaxf(sqrtf(ss), 1e-12f);
  }
}

// bundle mean-agg over BI buckets from MACC (bf16 item rows)
__global__ void k_agg_lds(const int2* __restrict__ binned, const int* __restrict__ bBase,
                          const int* __restrict__ cnt, const unsigned short* __restrict__ MACC,
                          float* __restrict__ ILB) {
  __shared__ float sAcc[128 * 65];
  int bk = BK_BI0 + blockIdx.x;
  int rowbase = bk << 7;
  int s = bBase[bk], e = bBase[bk + 1];
  for (int i = threadIdx.x; i < 128 * 65; i += 256) sAcc[i] = 0.0f;
  __syncthreads();
  int lane = threadIdx.x & 63, w = threadIdx.x >> 6;
  int q = lane >> 4, p = lane & 15;
  for (int base = s + (w << 2); base < e; base += 16) {
    int eidx = base + q;
    if (eidx < e) {
      int2 rc = binned[eidx];
      uint2 v = ((const uint2*)(MACC + (size_t)rc.y * 64))[p];
      float* dst = sAcc + (rc.x & 127) * 65 + p * 4;
      atomicAdd(dst + 0, __uint_as_float(v.x << 16));
      atomicAdd(dst + 1, __uint_as_float(v.x & 0xFFFF0000u));
      atomicAdd(dst + 2, __uint_as_float(v.y << 16));
      atomicAdd(dst + 3, __uint_as_float(v.y & 0xFFFF0000u));
    }
  }
  __syncthreads();
  for (int r = w; r < 128; r += 4) {
    int g = rowbase + r;
    int l = g - GBI0;
    if (l >= NBUc) continue;
    float wv = 1.0f / ((float)cnt[g] + 1e-8f);
    ILB[(size_t)l * 64 + lane] = sAcc[r * 65 + lane] * wv;
  }
}

// ACC (concat IL rows [0,150000) then BL rows [0,70000)) + item bf16 mirror
__global__ void k_acc_all(const float* __restrict__ userF, const float* __restrict__ bundF,
                          const float* __restrict__ itemF, const int* __restrict__ cnt,
                          const unsigned short* __restrict__ M1, const unsigned short* __restrict__ F2b,
                          const float* __restrict__ INV1, const float* __restrict__ INV2,
                          float* __restrict__ ACC, unsigned short* __restrict__ MACC) {
  long idx = (long)blockIdx.x * 256 + threadIdx.x;
  if (idx >= (long)(NILc + NBLc) * 64) return;
  int rl = (int)(idx >> 6), d = (int)(idx & 63);
  int g; float base;
  bool il = rl < NILc;
  if (il) {
    g = rl;
    base = (rl < NUc) ? userF[(long)rl * 64 + d] : itemF[(long)(rl - NUc) * 64 + d];
  } else {
    int l = rl - NILc;
    g = GUB0 + l;
    base = (l < NUc) ? userF[(long)l * 64 + d] : bundF[(long)(l - NUc) * 64 + d];
  }
  float rs = sqrtf((float)cnt[g]) + 1e-8f;              // 1/dinv
  float F1 = bf2f(M1[(size_t)g * 64 + d]) * rs;
  float F2 = bf2f(F2b[(size_t)g * 64 + d]);
  float res = base + F1 * INV1[g] + F2 * INV2[g];
  ACC[idx] = res;
  if (il && rl >= NUc) MACC[(size_t)(rl - NUc) * 64 + d] = f2bf(res);
}

// 4 batch gathers in one launch
__global__ void k_gather_all(const int* __restrict__ users, const int* __restrict__ bundles,
                             const float* __restrict__ ACC, const float* __restrict__ ILB, int B,
                             float* __restrict__ ILu, float* __restrict__ BLu,
                             float* __restrict__ ILb2, float* __restrict__ BLb2) {
  long i = (long)blockIdx.x * 256 + threadIdx.x;
  if (i >= (long)6 * B * 64) return;
  int r = (int)(i >> 6), d = (int)(i & 63);
  if (r < B) ILu[(long)r * 64 + d] = ACC[(long)users[r] * 64 + d];
  else if (r < 2 * B) { int rr = r - B; BLu[(long)rr * 64 + d] = ACC[(long)(NILc + users[rr]) * 64 + d]; }
  else if (r < 4 * B) { int rr = r - 2 * B; ILb2[(long)rr * 64 + d] = ILB[(long)bundles[rr] * 64 + d]; }
  else { int rr = r - 4 * B; BLb2[(long)rr * 64 + d] = ACC[(long)(NILc + NUc + bundles[rr]) * 64 + d]; }
}

__global__ void k_normalize4(const float* __restrict__ s0, const float* __restrict__ s1,
                             const float* __restrict__ s2, const float* __restrict__ s3,
                             float* __restrict__ d0, float* __restrict__ d1,
                             float* __restrict__ d2, float* __restrict__ d3, int B) {
  int row = blockIdx.x * 4 + (threadIdx.x >> 6);
  int lane = threadIdx.x & 63;
  if (row >= 4 * B) return;
  int which = row / B, r = row - which * B;
  const float* src; float* dst; int stride;
  if (which == 0)      { src = s0; dst = d0; stride = 64; }
  else if (which == 1) { src = s1; dst = d1; stride = 64; }
  else if (which == 2) { src = s2; dst = d2; stride = 128; }
  else                 { src = s3; dst = d3; stride = 128; }
  float v = src[(long)r * stride + lane];
  float ss = wredsum(v * v);
  dst[(long)r * 64 + lane] = v * (1.0f / fmaxf(sqrtf(ss), 1e-12f));
}

__global__ void k_bpr(const float* __restrict__ ILu, const float* __restrict__ ILb2,
                      const float* __restrict__ BLu, const float* __restrict__ BLb2,
                      int B, float* __restrict__ out) {
  int row = blockIdx.x * 4 + (threadIdx.x >> 6);
  int lane = threadIdx.x & 63;
  if (row >= B) return;
  float t = ILu[(long)row * 64 + lane] *
              (ILb2[(long)(2 * row) * 64 + lane] - ILb2[(long)(2 * row + 1) * 64 + lane]) +
            BLu[(long)row * 64 + lane] *
              (BLb2[(long)(2 * row) * 64 + lane] - BLb2[(long)(2 * row + 1) * 64 + lane]);
  float x = wredsum(t);
  if (lane == 0) {
    float ls = -(fmaxf(-x, 0.0f) + log1pf(expf(-fabsf(x))));
    unsafeAtomicAdd(&out[0], -ls / (float)B);
  }
}

// InfoNCE GEMM, z selects (P,A,S) pair; conflict-free stride-16 columns
__global__ void k_gemm_nt2(const float* __restrict__ P1, const float* __restrict__ A1,
                           const float* __restrict__ P2, const float* __restrict__ A2,
                           float* __restrict__ S1o, float* __restrict__ S2o,
                           int N, float scale) {
  __shared__ float Ps[64][129];
  __shared__ float As[64][129];
  const float* P = blockIdx.z ? P2 : P1;
  const float* A = blockIdx.z ? A2 : A1;
  float* S = blockIdx.z ? S2o : S1o;
  int bi0 = blockIdx.y * 128, bj0 = blockIdx.x * 128;
  int t = threadIdx.x;
  #pragma unroll
  for (int sct = 0; sct < 8; sct++) {
    int idx4 = t + sct * 256;
    int r = idx4 >> 4, k = (idx4 & 15) << 2;
    int pr = min(bi0 + r, N - 1);
    int ar = min(bj0 + r, N - 1);
    float4 v = *(const float4*)(P + (long)pr * 64 + k);
    Ps[k][r] = v.x; Ps[k + 1][r] = v.y; Ps[k + 2][r] = v.z; Ps[k + 3][r] = v.w;
    float4 w = *(const float4*)(A + (long)ar * 64 + k);
    As[k][r] = w.x; As[k + 1][r] = w.y; As[k + 2][r] = w.z; As[k + 3][r] = w.w;
  }
  __syncthreads();
  int tx = t & 15, ty = t >> 4;
  float acc[8][8];
  #pragma unroll
  for (int i = 0; i < 8; i++)
    #pragma unroll
    for (int j = 0; j < 8; j++) acc[i][j] = 0.0f;
  #pragma unroll 4
  for (int k = 0; k < 64; k++) {
    float a[8], b[8];
    #pragma unroll
    for (int i = 0; i < 8; i++) a[i] = Ps[k][ty * 8 + i];
    #pragma unroll
    for (int j = 0; j < 8; j++) b[j] = As[k][tx + 16 * j];
    #pragma unroll
    for (int i = 0; i < 8; i++)
      #pragma unroll
      for (int j = 0; j < 8; j++) acc[i][j] = fmaf(a[i], b[j], acc[i][j]);
  }
  #pragma unroll
  for (int i = 0; i < 8; i++) {
    int row = bi0 + ty * 8 + i;
    if (row >= N) continue;
    #pragma unroll
    for (int j = 0; j < 8; j++) {
      int cc = bj0 + tx + 16 * j;
      if (cc < N) S[(long)row * N + cc] = acc[i][j] * scale;
    }
  }
}

// merged LSE over S1 (rows [0,B)) and S2 (rows [B,2B))
__global__ void k_lse2(const float* __restrict__ S1, const float* __restrict__ S2,
                       int B, float coeff, float* __restrict__ out) {
  constexpr float L2E = 1.44269504f;
  int row = blockIdx.x * 4 + (threadIdx.x >> 6);
  int lane = threadIdx.x & 63;
  const float* Sr; int dg;
  if (row < B) { Sr = S1 + (long)row * B; dg = row; }
  else         { Sr = S2 + (long)(row - B) * B; dg = row - B; }
  float m = -1e30f, s = 0.0f;
  for (int w = 0; w < (B >> 8); w++) {
    float4 v = *(const float4*)(Sr + ((w << 6) + lane) * 4);
    float mx = fmaxf(fmaxf(v.x, v.y), fmaxf(v.z, v.w));
    if (mx > m) { s *= exp2f((m - mx) * L2E); m = mx; }
    s += exp2f((v.x - m) * L2E) + exp2f((v.y - m) * L2E) +
         exp2f((v.z - m) * L2E) + exp2f((v.w - m) * L2E);
  }
  #pragma unroll
  for (int o = 32; o >= 1; o >>= 1) {
    float m2 = __shfl_xor(m, o, 64), s2 = __shfl_xor(s, o, 64);
    float M = fmaxf(m, m2);
    s = s * exp2f((m - M) * L2E) + s2 * exp2f((m2 - M) * L2E);
    m = M;
  }
  if (lane == 0) {
    float lse = m + log2f(s) * 0.69314718f;
    unsafeAtomicAdd(&out[1], -(Sr[dg] - lse) * coeff);
  }
}

extern "C" void kernel_launch(void* const* d_in, const int* in_sizes, int n_in,
                              void* d_out, int out_size, void* d_ws, size_t ws_size,
                              hipStream_t stream) {
  const int* users   = (const int*)d_in[0];
  const int* bundles = (const int*)d_in[1];
  const int* ui_u    = (const int*)d_in[2];
  const int* ui_i    = (const int*)d_in[3];
  const int* ub_u    = (const int*)d_in[4];
  const int* ub_b    = (const int*)d_in[5];
  const int* bi_b    = (const int*)d_in[6];
  const int* bi_i    = (const int*)d_in[7];
  const float* userF = (const float*)d_in[8];
  const float* bundF = (const float*)d_in[9];
  const float* itemF = (const float*)d_in[10];
  float* out = (float*)d_out;

  const int B    = in_sizes[0];
  const int E_ui = in_sizes[2];
  const int E_ub = in_sizes[4];
  const int E_bi = in_sizes[6];
  const long E_all = 2L * E_ui + 2L * E_ub + E_bi;

  float* ws = (float*)d_ws;
  size_t off = 0;
  auto alloc = [&](size_t nfloat) -> float* {
    float* p = ws + off;
    off += (nfloat + 63) & ~(size_t)63;
    return p;
  };
  float* ACC = alloc((size_t)(NILc + NBLc) * 64);            // 56.3 MB
  unsigned short* X  = (unsigned short*)alloc((size_t)GBI0 * 32);  // bf16, 28.2 MB
  unsigned short* M1 = (unsigned short*)alloc((size_t)GBI0 * 32);  // bf16, 28.2 MB
  int2* binned = (int2*)alloc((size_t)E_all * 2);            // 48 MB
  int* cnt   = (int*)alloc(GTOT);
  float* INV1 = alloc(GTOT);
  float* INV2 = alloc(GTOT);
  float* ILB  = alloc((size_t)NBUc * 64);
  float* ILu  = alloc((size_t)B * 64);
  float* BLu  = alloc((size_t)B * 64);
  float* ILb2 = alloc((size_t)B * 128);
  float* BLb2 = alloc((size_t)B * 128);
  float* PN1  = alloc((size_t)B * 64);
  float* AN1  = alloc((size_t)B * 64);
  float* PN2  = alloc((size_t)B * 64);
  float* AN2  = alloc((size_t)B * 64);
  int* bCnt  = (int*)alloc(2049);
  int* bBase = (int*)alloc(2049);
  int* bCur  = (int*)alloc(2049);
  (void)ws_size; (void)n_in; (void)out_size;

  // aliases into dead phases:
  unsigned short* F2b  = X;                     // spmm2 output overlays X (dead after spmm1)
  unsigned short* MACC = (unsigned short*)binned;  // 12.8MB < UI/UB binned segment (dead after spmm2);
                                                   // BI segment lives at >=40MB offset
  float* S1 = ACC;                              // ACC dead after gathers
  float* S2 = ACC + (size_t)B * B;

  // ---- bucketed binning of all 3 graphs (one global padded row space) ----
  hipMemsetAsync(bCnt, 0, sizeof(int) * NBK, stream);
  k_bcount_all<<<1024, 256, 0, stream>>>(ui_u, ui_i, ub_u, ub_b, bi_b, E_ui, E_ub, E_bi, bCnt);
  k_scan2048<<<1, 512, 0, stream>>>(bCnt, NBK, bBase, bCur);
  k_bin_all<<<1024, 256, 0, stream>>>(ui_u, ui_i, ub_u, ub_b, bi_b, bi_i,
                                      E_ui, E_ub, E_bi, bCur, binned);
  k_rowhist_all<<<NBK, 256, 0, stream>>>(binned, bBase, cnt);

  // ---- propagate (UI + UB merged per layer) ----
  k_prescale_all<<<(int)(((long)GBI0 * 64 + 255) / 256), 256, 0, stream>>>(cnt, userF, bundF,
                                                                           itemF, X);
  k_spmm_lds<<<BK_BI0, 256, 0, stream>>>(binned, bBase, cnt, X, M1, INV1, 0.5f, 1);
  k_spmm_lds<<<BK_BI0, 256, 0, stream>>>(binned, bBase, cnt, M1, F2b, INV2, 1.0f / 3.0f, 0);
  k_acc_all<<<(int)(((long)(NILc + NBLc) * 64 + 255) / 256), 256, 0, stream>>>(
      userF, bundF, itemF, cnt, M1, F2b, INV1, INV2, ACC, MACC);
  k_agg_lds<<<NBK - BK_BI0, 256, 0, stream>>>(binned, bBase, cnt, MACC, ILB);
  k_gather_all<<<(int)(((long)6 * B * 64 + 255) / 256), 256, 0, stream>>>(
      users, bundles, ACC, ILB, B, ILu, BLu, ILb2, BLb2);

  // ---- losses ----
  hipMemsetAsync(out, 0, 2 * sizeof(float), stream);
  k_bpr<<<(B + 3) / 4, 256, 0, stream>>>(ILu, ILb2, BLu, BLb2, B, out);
  k_normalize4<<<(4 * B + 3) / 4, 256, 0, stream>>>(ILu, BLu, ILb2, BLb2, PN1, AN1, PN2, AN2, B);
  dim3 gg((B + 127) / 128, (B + 127) / 128, 2);
  k_gemm_nt2<<<gg, 256, 0, stream>>>(PN1, AN1, PN2, AN2, S1, S2, B, 4.0f);  // 1/C_TEMP
  k_lse2<<<(2 * B + 3) / 4, 256, 0, stream>>>(S1, S2, B, 0.5f / (float)B, out);
}

// Round 10
// 612.200 us; speedup vs baseline: 8.5726x; 8.5726x over previous
//
#include <hip/hip_runtime.h>
#include <hip/hip_bf16.h>
#include <math.h>

// CrossCBR R10: revert to proven quarter-wave GATHER SpMM (R9's LDS float
// atomics were CAS loops -> 25x slowdown). Keep R9's consolidation: one global
// padded row space, single binning pass for all 3 graphs, unified CSR, merged
// UI+UB SpMM per layer, bf16-only intermediate layers (F1 reconstructed in acc).
static constexpr int NUc  = 50000;
static constexpr int NBUc = 20000;
static constexpr int NIc  = 100000;
static constexpr int NILc = 150000;           // UI graph nodes
static constexpr int NBLc = 70000;            // UB graph nodes
// global padded rows: UI [0,150016), UB [150016,220032), BI [220032,240128)
static constexpr int GUB0   = 150016;         // 1172*128
static constexpr int GBI0   = 220032;         // 1719*128
static constexpr int BK_UB0 = 1172;
static constexpr int BK_BI0 = 1719;
static constexpr int NBK    = 1876;
static constexpr int GTOT   = NBK * 128;      // 240128

__device__ __forceinline__ float wredsum(float v) {
  #pragma unroll
  for (int m = 32; m >= 1; m >>= 1) v += __shfl_xor(v, m, 64);
  return v;
}
__device__ __forceinline__ float bf2f(unsigned short h) {
  return __uint_as_float(((unsigned int)h) << 16);
}
__device__ __forceinline__ unsigned short f2bf(float f) {  // RNE
  unsigned int u = __float_as_uint(f);
  return (unsigned short)((u + 0x7FFFu + ((u >> 16) & 1u)) >> 16);
}

// ---------------- bucket counts (all 3 graphs, one launch) ----------------
__global__ void k_bcount_all(const int* __restrict__ ui_u, const int* __restrict__ ui_i,
                             const int* __restrict__ ub_u, const int* __restrict__ ub_b,
                             const int* __restrict__ bi_b,
                             int E_ui, int E_ub, int E_bi, int* __restrict__ bCnt) {
  __shared__ int hist[NBK];
  for (int i = threadIdx.x; i < NBK; i += 256) hist[i] = 0;
  __syncthreads();
  int b = blockIdx.x;
  if (b < 512) {
    int chunk = (E_ui + 511) / 512, c0 = b * chunk, c1 = min(E_ui, c0 + chunk);
    for (int e = c0 + (int)threadIdx.x; e < c1; e += 256) {
      atomicAdd(&hist[ui_u[e] >> 7], 1);
      atomicAdd(&hist[(ui_i[e] + NUc) >> 7], 1);
    }
  } else if (b < 768) {
    int lb = b - 512, chunk = (E_ub + 255) / 256, c0 = lb * chunk, c1 = min(E_ub, c0 + chunk);
    for (int e = c0 + (int)threadIdx.x; e < c1; e += 256) {
      atomicAdd(&hist[(GUB0 + ub_u[e]) >> 7], 1);
      atomicAdd(&hist[(GUB0 + NUc + ub_b[e]) >> 7], 1);
    }
  } else {
    int lb = b - 768, chunk = (E_bi + 255) / 256, c0 = lb * chunk, c1 = min(E_bi, c0 + chunk);
    for (int e = c0 + (int)threadIdx.x; e < c1; e += 256)
      atomicAdd(&hist[(GBI0 + bi_b[e]) >> 7], 1);
  }
  __syncthreads();
  for (int i = threadIdx.x; i < NBK; i += 256)
    if (hist[i]) atomicAdd(&bCnt[i], hist[i]);
}

// exclusive scan of n<=2048 elements, 1 block x 512
__global__ void k_scan2048(const int* __restrict__ in, int n,
                           int* __restrict__ outBase, int* __restrict__ outCur) {
  __shared__ int sh[512];
  int t = threadIdx.x, i0 = 4 * t;
  int v0 = (i0 < n) ? in[i0] : 0;
  int v1 = (i0 + 1 < n) ? in[i0 + 1] : 0;
  int v2 = (i0 + 2 < n) ? in[i0 + 2] : 0;
  int v3 = (i0 + 3 < n) ? in[i0 + 3] : 0;
  int ts = v0 + v1 + v2 + v3;
  sh[t] = ts;
  __syncthreads();
  for (int o = 1; o < 512; o <<= 1) {
    int x = (t >= o) ? sh[t - o] : 0;
    __syncthreads();
    sh[t] += x;
    __syncthreads();
  }
  int ex = sh[t] - ts;
  if (i0 < n)     { outBase[i0] = ex;                    outCur[i0] = ex; }
  if (i0 + 1 < n) { outBase[i0 + 1] = ex + v0;           outCur[i0 + 1] = ex + v0; }
  if (i0 + 2 < n) { outBase[i0 + 2] = ex + v0 + v1;      outCur[i0 + 2] = ex + v0 + v1; }
  if (i0 + 3 < n) { outBase[i0 + 3] = ex + v0 + v1 + v2; outCur[i0 + 3] = ex + v0 + v1 + v2; }
  if (t == 511) outBase[n] = sh[511];
}

// ---------------- bin all edges -> bucket-sorted (row,col) pairs ----------------
__global__ void k_bin_all(const int* __restrict__ ui_u, const int* __restrict__ ui_i,
                          const int* __restrict__ ub_u, const int* __restrict__ ub_b,
                          const int* __restrict__ bi_b, const int* __restrict__ bi_i,
                          int E_ui, int E_ub, int E_bi,
                          int* __restrict__ bCur, int2* __restrict__ binned) {
  __shared__ int hist[NBK];
  __shared__ int base[NBK];
  for (int i = threadIdx.x; i < NBK; i += 256) hist[i] = 0;
  __syncthreads();
  int b = blockIdx.x;
  int c0, c1, seg;
  if (b < 512)      { seg = 0; int ch = (E_ui + 511) / 512; c0 = b * ch; c1 = min(E_ui, c0 + ch); }
  else if (b < 768) { seg = 1; int ch = (E_ub + 255) / 256; c0 = (b - 512) * ch; c1 = min(E_ub, c0 + ch); }
  else              { seg = 2; int ch = (E_bi + 255) / 256; c0 = (b - 768) * ch; c1 = min(E_bi, c0 + ch); }
  for (int e = c0 + (int)threadIdx.x; e < c1; e += 256) {
    if (seg == 0) {
      atomicAdd(&hist[ui_u[e] >> 7], 1);
      atomicAdd(&hist[(ui_i[e] + NUc) >> 7], 1);
    } else if (seg == 1) {
      atomicAdd(&hist[(GUB0 + ub_u[e]) >> 7], 1);
      atomicAdd(&hist[(GUB0 + NUc + ub_b[e]) >> 7], 1);
    } else {
      atomicAdd(&hist[(GBI0 + bi_b[e]) >> 7], 1);
    }
  }
  __syncthreads();
  for (int i = threadIdx.x; i < NBK; i += 256) {
    int h = hist[i];
    base[i] = h ? atomicAdd(&bCur[i], h) : 0;
    hist[i] = 0;
  }
  __syncthreads();
  for (int e = c0 + (int)threadIdx.x; e < c1; e += 256) {
    if (seg == 0) {
      int u = ui_u[e], x = ui_i[e] + NUc;  // cols already X-global (base 0)
      int b1 = u >> 7; binned[base[b1] + atomicAdd(&hist[b1], 1)] = make_int2(u, x);
      int b2 = x >> 7; binned[base[b2] + atomicAdd(&hist[b2], 1)] = make_int2(x, u);
    } else if (seg == 1) {
      int ul = ub_u[e], bl = NUc + ub_b[e];
      int r1 = GUB0 + ul, r2 = GUB0 + bl;
      int b1 = r1 >> 7; binned[base[b1] + atomicAdd(&hist[b1], 1)] = make_int2(r1, bl);
      int b2 = r2 >> 7; binned[base[b2] + atomicAdd(&hist[b2], 1)] = make_int2(r2, ul);
    } else {
      int r = GBI0 + bi_b[e];
      int b1 = r >> 7; binned[base[b1] + atomicAdd(&hist[b1], 1)] = make_int2(r, bi_i[e]);
    }
  }
}

// per-row degree (covers all padded rows)
__global__ void k_rowhist_all(const int2* __restrict__ binned, const int* __restrict__ bBase,
                              int* __restrict__ cnt) {
  __shared__ int hist[128];
  int bk = blockIdx.x, rowbase = bk << 7;
  int s = bBase[bk], e = bBase[bk + 1];
  if (threadIdx.x < 128) hist[threadIdx.x] = 0;
  __syncthreads();
  for (int i = s + (int)threadIdx.x; i < e; i += 256)
    atomicAdd(&hist[binned[i].x & 127], 1);
  __syncthreads();
  if (threadIdx.x < 128) cnt[rowbase + (int)threadIdx.x] = hist[threadIdx.x];
}

// hierarchical scan for rp over GTOT+1 elements
__global__ void k_scan_block(const int* __restrict__ in, int n, int* __restrict__ out,
                             int* __restrict__ bsum) {
  __shared__ int sh[256];
  int t = threadIdx.x;
  long base = (long)blockIdx.x * 1024 + (long)t * 4;
  int v0 = (base     < n) ? in[base]     : 0;
  int v1 = (base + 1 < n) ? in[base + 1] : 0;
  int v2 = (base + 2 < n) ? in[base + 2] : 0;
  int v3 = (base + 3 < n) ? in[base + 3] : 0;
  int tsum = v0 + v1 + v2 + v3;
  sh[t] = tsum;
  __syncthreads();
  for (int o = 1; o < 256; o <<= 1) {
    int x = (t >= o) ? sh[t - o] : 0;
    __syncthreads();
    sh[t] += x;
    __syncthreads();
  }
  int excl = sh[t] - tsum;
  if (t == 255) bsum[blockIdx.x] = sh[255];
  if (base     < n) out[base]     = excl;
  if (base + 1 < n) out[base + 1] = excl + v0;
  if (base + 2 < n) out[base + 2] = excl + v0 + v1;
  if (base + 3 < n) out[base + 3] = excl + v0 + v1 + v2;
}

__global__ void k_scan_bsum(int* __restrict__ bsum, int nb) {  // nb <= 256
  __shared__ int sh[256];
  int t = threadIdx.x;
  int v = (t < nb) ? bsum[t] : 0;
  sh[t] = v;
  __syncthreads();
  for (int o = 1; o < 256; o <<= 1) {
    int x = (t >= o) ? sh[t - o] : 0;
    __syncthreads();
    sh[t] += x;
    __syncthreads();
  }
  if (t < nb) bsum[t] = sh[t] - v;
}

__global__ void k_scan_add(int* __restrict__ out, int n, const int* __restrict__ bsum) {
  long i = (long)blockIdx.x * 256 + threadIdx.x;
  if (i < n) out[i] += bsum[i >> 10];
}

// per-bucket CSR fill; col = X-global column (UB cols shifted by GUB0)
__global__ void k_csrfill_all(const int2* __restrict__ binned, const int* __restrict__ bBase,
                              const int* __restrict__ rp, int* __restrict__ colv) {
  __shared__ int cur[128];
  int bk = blockIdx.x, rowbase = bk << 7;
  int xb = (bk < BK_UB0) ? 0 : ((bk < BK_BI0) ? GUB0 : 0);  // BI cols stay item-local
  int s = bBase[bk], e = bBase[bk + 1];
  if (threadIdx.x < 128) cur[threadIdx.x] = rp[rowbase + (int)threadIdx.x];
  __syncthreads();
  for (int i = s + (int)threadIdx.x; i < e; i += 256) {
    int2 rc = binned[i];
    int pos = atomicAdd(&cur[rc.x & 127], 1);
    colv[pos] = xb + rc.y;
  }
}

// X[g] = f2bf(feat[g] * dinv[g]) over [0, GBI0)
__global__ void k_prescale_all(const int* __restrict__ cnt, const float* __restrict__ userF,
                               const float* __restrict__ bundF, const float* __restrict__ itemF,
                               unsigned short* __restrict__ X) {
  long idx = (long)blockIdx.x * 256 + threadIdx.x;
  if (idx >= (long)GBI0 * 64) return;
  int g = (int)(idx >> 6), d = (int)(idx & 63);
  float v = 0.0f;
  if (g < NILc) v = (g < NUc) ? userF[(long)g * 64 + d] : itemF[(long)(g - NUc) * 64 + d];
  else if (g >= GUB0 && g < GUB0 + NBLc) {
    int l = g - GUB0;
    v = (l < NUc) ? userF[(long)l * 64 + d] : bundF[(long)(l - NUc) * 64 + d];
  }
  float dinv = 1.0f / (sqrtf((float)cnt[g]) + 1e-8f);
  X[idx] = f2bf(v * dinv);
}

// ---------------- quarter-wave gather SpMM (R8-proven inner loop) ----------
// outB[g] = f2bf(res * (mulDinv?dinv:1)); outInv[g] = 1/max(||res||,eps)
__global__ void k_spmm_g(const int* __restrict__ rp, const int* __restrict__ col,
                         const unsigned short* __restrict__ X,
                         unsigned short* __restrict__ outB, float* __restrict__ outInv,
                         float scale, int mulDinv, int n) {
  int row = blockIdx.x * 4 + (threadIdx.x >> 6);
  int lane = threadIdx.x & 63;
  if (row >= n) return;
  int q = lane >> 4, p = lane & 15;
  int s = rp[row], e = rp[row + 1];
  float dinv = 1.0f / (sqrtf((float)(e - s)) + 1e-8f);
  float a0 = 0.f, a1 = 0.f, a2 = 0.f, a3 = 0.f;
  for (int chunk = s; chunk < e; chunk += 64) {
    int nc = min(64, e - chunk);
    int ci = (lane < nc) ? col[chunk + lane] : 0;
    int nit = (nc + 3) >> 2;
    for (int it = 0; it < nit; it++) {
      int eidx = (it << 2) + q;
      int c = __shfl(ci, min(eidx, nc - 1), 64);
      uint2 v = ((const uint2*)(X + (size_t)c * 64))[p];
      if (eidx >= nc) { v.x = 0u; v.y = 0u; }
      a0 += __uint_as_float(v.x << 16);
      a1 += __uint_as_float(v.x & 0xFFFF0000u);
      a2 += __uint_as_float(v.y << 16);
      a3 += __uint_as_float(v.y & 0xFFFF0000u);
    }
  }
  a0 += __shfl_xor(a0, 32, 64); a1 += __shfl_xor(a1, 32, 64);
  a2 += __shfl_xor(a2, 32, 64); a3 += __shfl_xor(a3, 32, 64);
  a0 += __shfl_xor(a0, 16, 64); a1 += __shfl_xor(a1, 16, 64);
  a2 += __shfl_xor(a2, 16, 64); a3 += __shfl_xor(a3, 16, 64);
  float f = dinv * scale;
  float r0 = a0 * f, r1 = a1 * f, r2 = a2 * f, r3 = a3 * f;
  float ss = r0 * r0 + r1 * r1 + r2 * r2 + r3 * r3;
  ss += __shfl_xor(ss, 8, 64);
  ss += __shfl_xor(ss, 4, 64);
  ss += __shfl_xor(ss, 2, 64);
  ss += __shfl_xor(ss, 1, 64);
  if (q == 0) {
    float mf = mulDinv ? dinv : 1.0f;
    uint2 m;
    m.x = (unsigned int)f2bf(r0 * mf) | ((unsigned int)f2bf(r1 * mf) << 16);
    m.y = (unsigned int)f2bf(r2 * mf) | ((unsigned int)f2bf(r3 * mf) << 16);
    *(uint2*)(outB + (size_t)row * 64 + p * 4) = m;
    if (p == 0) outInv[row] = 1.0f / fmaxf(sqrtf(ss), 1e-12f);
  }
}

// vectorized bundle mean-agg (BI rows of unified CSR; cols index MACC)
__global__ void k_agg_g(const int* __restrict__ rp, const int* __restrict__ col,
                        const unsigned short* __restrict__ MACC, float* __restrict__ ILB, int n) {
  int rl = blockIdx.x * 4 + (threadIdx.x >> 6);
  int lane = threadIdx.x & 63;
  if (rl >= n) return;
  int row = GBI0 + rl;
  int q = lane >> 4, p = lane & 15;
  int s = rp[row], e = rp[row + 1];
  float a0 = 0.f, a1 = 0.f, a2 = 0.f, a3 = 0.f;
  for (int chunk = s; chunk < e; chunk += 64) {
    int nc = min(64, e - chunk);
    int ci = (lane < nc) ? col[chunk + lane] : 0;
    int nit = (nc + 3) >> 2;
    for (int it = 0; it < nit; it++) {
      int eidx = (it << 2) + q;
      int c = __shfl(ci, min(eidx, nc - 1), 64);
      uint2 v = ((const uint2*)(MACC + (size_t)c * 64))[p];
      if (eidx >= nc) { v.x = 0u; v.y = 0u; }
      a0 += __uint_as_float(v.x << 16);
      a1 += __uint_as_float(v.x & 0xFFFF0000u);
      a2 += __uint_as_float(v.y << 16);
      a3 += __uint_as_float(v.y & 0xFFFF0000u);
    }
  }
  a0 += __shfl_xor(a0, 32, 64); a1 += __shfl_xor(a1, 32, 64);
  a2 += __shfl_xor(a2, 32, 64); a3 += __shfl_xor(a3, 32, 64);
  a0 += __shfl_xor(a0, 16, 64); a1 += __shfl_xor(a1, 16, 64);
  a2 += __shfl_xor(a2, 16, 64); a3 += __shfl_xor(a3, 16, 64);
  if (q == 0) {
    float w = 1.0f / ((float)(e - s) + 1e-8f);
    *(float4*)(ILB + (size_t)rl * 64 + p * 4) = make_float4(a0 * w, a1 * w, a2 * w, a3 * w);
  }
}

// ACC (IL rows then BL rows) + bf16 item mirror; F1 reconstructed from M1
__global__ void k_acc_all(const float* __restrict__ userF, const float* __restrict__ bundF,
                          const float* __restrict__ itemF, const int* __restrict__ cnt,
                          const unsigned short* __restrict__ M1, const unsigned short* __restrict__ F2b,
                          const float* __restrict__ INV1, const float* __restrict__ INV2,
                          float* __restrict__ ACC, unsigned short* __restrict__ MACC) {
  long idx = (long)blockIdx.x * 256 + threadIdx.x;
  if (idx >= (long)(NILc + NBLc) * 64) return;
  int rl = (int)(idx >> 6), d = (int)(idx & 63);
  int g; float base;
  bool il = rl < NILc;
  if (il) {
    g = rl;
    base = (rl < NUc) ? userF[(long)rl * 64 + d] : itemF[(long)(rl - NUc) * 64 + d];
  } else {
    int l = rl - NILc;
    g = GUB0 + l;
    base = (l < NUc) ? userF[(long)l * 64 + d] : bundF[(long)(l - NUc) * 64 + d];
  }
  float rs = sqrtf((float)cnt[g]) + 1e-8f;   // 1/dinv
  float F1 = bf2f(M1[(size_t)g * 64 + d]) * rs;
  float F2 = bf2f(F2b[(size_t)g * 64 + d]);
  float res = base + F1 * INV1[g] + F2 * INV2[g];
  ACC[idx] = res;
  if (il && rl >= NUc) MACC[(size_t)(rl - NUc) * 64 + d] = f2bf(res);
}

__global__ void k_gather_all(const int* __restrict__ users, const int* __restrict__ bundles,
                             const float* __restrict__ ACC, const float* __restrict__ ILB, int B,
                             float* __restrict__ ILu, float* __restrict__ BLu,
                             float* __restrict__ ILb2, float* __restrict__ BLb2) {
  long i = (long)blockIdx.x * 256 + threadIdx.x;
  if (i >= (long)6 * B * 64) return;
  int r = (int)(i >> 6), d = (int)(i & 63);
  if (r < B) ILu[(long)r * 64 + d] = ACC[(long)users[r] * 64 + d];
  else if (r < 2 * B) { int rr = r - B; BLu[(long)rr * 64 + d] = ACC[(long)(NILc + users[rr]) * 64 + d]; }
  else if (r < 4 * B) { int rr = r - 2 * B; ILb2[(long)rr * 64 + d] = ILB[(long)bundles[rr] * 64 + d]; }
  else { int rr = r - 4 * B; BLb2[(long)rr * 64 + d] = ACC[(long)(NILc + NUc + bundles[rr]) * 64 + d]; }
}

__global__ void k_normalize4(const float* __restrict__ s0, const float* __restrict__ s1,
                             const float* __restrict__ s2, const float* __restrict__ s3,
                             float* __restrict__ d0, float* __restrict__ d1,
                             float* __restrict__ d2, float* __restrict__ d3, int B) {
  int row = blockIdx.x * 4 + (threadIdx.x >> 6);
  int lane = threadIdx.x & 63;
  if (row >= 4 * B) return;
  int which = row / B, r = row - which * B;
  const float* src; float* dst; int stride;
  if (which == 0)      { src = s0; dst = d0; stride = 64; }
  else if (which == 1) { src = s1; dst = d1; stride = 64; }
  else if (which == 2) { src = s2; dst = d2; stride = 128; }
  else                 { src = s3; dst = d3; stride = 128; }
  float v = src[(long)r * stride + lane];
  float ss = wredsum(v * v);
  dst[(long)r * 64 + lane] = v * (1.0f / fmaxf(sqrtf(ss), 1e-12f));
}

__global__ void k_bpr(const float* __restrict__ ILu, const float* __restrict__ ILb2,
                      const float* __restrict__ BLu, const float* __restrict__ BLb2,
                      int B, float* __restrict__ out) {
  int row = blockIdx.x * 4 + (threadIdx.x >> 6);
  int lane = threadIdx.x & 63;
  if (row >= B) return;
  float t = ILu[(long)row * 64 + lane] *
              (ILb2[(long)(2 * row) * 64 + lane] - ILb2[(long)(2 * row + 1) * 64 + lane]) +
            BLu[(long)row * 64 + lane] *
              (BLb2[(long)(2 * row) * 64 + lane] - BLb2[(long)(2 * row + 1) * 64 + lane]);
  float x = wredsum(t);
  if (lane == 0) {
    float ls = -(fmaxf(-x, 0.0f) + log1pf(expf(-fabsf(x))));
    unsafeAtomicAdd(&out[0], -ls / (float)B);
  }
}

// InfoNCE GEMM, z selects pair; conflict-free stride-16 columns
__global__ void k_gemm_nt2(const float* __restrict__ P1, const float* __restrict__ A1,
                           const float* __restrict__ P2, const float* __restrict__ A2,
                           float* __restrict__ S1o, float* __restrict__ S2o,
                           int N, float scale) {
  __shared__ float Ps[64][129];
  __shared__ float As[64][129];
  const float* P = blockIdx.z ? P2 : P1;
  const float* A = blockIdx.z ? A2 : A1;
  float* S = blockIdx.z ? S2o : S1o;
  int bi0 = blockIdx.y * 128, bj0 = blockIdx.x * 128;
  int t = threadIdx.x;
  #pragma unroll
  for (int sct = 0; sct < 8; sct++) {
    int idx4 = t + sct * 256;
    int r = idx4 >> 4, k = (idx4 & 15) << 2;
    int pr = min(bi0 + r, N - 1);
    int ar = min(bj0 + r, N - 1);
    float4 v = *(const float4*)(P + (long)pr * 64 + k);
    Ps[k][r] = v.x; Ps[k + 1][r] = v.y; Ps[k + 2][r] = v.z; Ps[k + 3][r] = v.w;
    float4 w = *(const float4*)(A + (long)ar * 64 + k);
    As[k][r] = w.x; As[k + 1][r] = w.y; As[k + 2][r] = w.z; As[k + 3][r] = w.w;
  }
  __syncthreads();
  int tx = t & 15, ty = t >> 4;
  float acc[8][8];
  #pragma unroll
  for (int i = 0; i < 8; i++)
    #pragma unroll
    for (int j = 0; j < 8; j++) acc[i][j] = 0.0f;
  #pragma unroll 4
  for (int k = 0; k < 64; k++) {
    float a[8], b[8];
    #pragma unroll
    for (int i = 0; i < 8; i++) a[i] = Ps[k][ty * 8 + i];
    #pragma unroll
    for (int j = 0; j < 8; j++) b[j] = As[k][tx + 16 * j];
    #pragma unroll
    for (int i = 0; i < 8; i++)
      #pragma unroll
      for (int j = 0; j < 8; j++) acc[i][j] = fmaf(a[i], b[j], acc[i][j]);
  }
  #pragma unroll
  for (int i = 0; i < 8; i++) {
    int row = bi0 + ty * 8 + i;
    if (row >= N) continue;
    #pragma unroll
    for (int j = 0; j < 8; j++) {
      int cc = bj0 + tx + 16 * j;
      if (cc < N) S[(long)row * N + cc] = acc[i][j] * scale;
    }
  }
}

__global__ void k_lse2(const float* __restrict__ S1, const float* __restrict__ S2,
                       int B, float coeff, float* __restrict__ out) {
  constexpr float L2E = 1.44269504f;
  int row = blockIdx.x * 4 + (threadIdx.x >> 6);
  int lane = threadIdx.x & 63;
  const float* Sr; int dg;
  if (row < B) { Sr = S1 + (long)row * B; dg = row; }
  else         { Sr = S2 + (long)(row - B) * B; dg = row - B; }
  float m = -1e30f, s = 0.0f;
  for (int w = 0; w < (B >> 8); w++) {
    float4 v = *(const float4*)(Sr + ((w << 6) + lane) * 4);
    float mx = fmaxf(fmaxf(v.x, v.y), fmaxf(v.z, v.w));
    if (mx > m) { s *= exp2f((m - mx) * L2E); m = mx; }
    s += exp2f((v.x - m) * L2E) + exp2f((v.y - m) * L2E) +
         exp2f((v.z - m) * L2E) + exp2f((v.w - m) * L2E);
  }
  #pragma unroll
  for (int o = 32; o >= 1; o >>= 1) {
    float m2 = __shfl_xor(m, o, 64), s2 = __shfl_xor(s, o, 64);
    float M = fmaxf(m, m2);
    s = s * exp2f((m - M) * L2E) + s2 * exp2f((m2 - M) * L2E);
    m = M;
  }
  if (lane == 0) {
    float lse = m + log2f(s) * 0.69314718f;
    unsafeAtomicAdd(&out[1], -(Sr[dg] - lse) * coeff);
  }
}

extern "C" void kernel_launch(void* const* d_in, const int* in_sizes, int n_in,
                              void* d_out, int out_size, void* d_ws, size_t ws_size,
                              hipStream_t stream) {
  const int* users   = (const int*)d_in[0];
  const int* bundles = (const int*)d_in[1];
  const int* ui_u    = (const int*)d_in[2];
  const int* ui_i    = (const int*)d_in[3];
  const int* ub_u    = (const int*)d_in[4];
  const int* ub_b    = (const int*)d_in[5];
  const int* bi_b    = (const int*)d_in[6];
  const int* bi_i    = (const int*)d_in[7];
  const float* userF = (const float*)d_in[8];
  const float* bundF = (const float*)d_in[9];
  const float* itemF = (const float*)d_in[10];
  float* out = (float*)d_out;

  const int B    = in_sizes[0];
  const int E_ui = in_sizes[2];
  const int E_ub = in_sizes[4];
  const int E_bi = in_sizes[6];
  const long E_all = 2L * E_ui + 2L * E_ub + E_bi;  // 6M directed edges

  float* ws = (float*)d_ws;
  size_t off = 0;
  auto alloc = [&](size_t nfloat) -> float* {
    float* p = ws + off;
    off += (nfloat + 63) & ~(size_t)63;
    return p;
  };
  float* ACC = alloc((size_t)(NILc + NBLc) * 64);                 // 56.3 MB
  unsigned short* X  = (unsigned short*)alloc((size_t)GBI0 * 32); // 28.2 MB
  unsigned short* M1 = (unsigned short*)alloc((size_t)GBI0 * 32); // 28.2 MB
  int2* binned = (int2*)alloc((size_t)E_all * 2);                 // 48 MB
  int* colv  = (int*)alloc((size_t)E_all);                        // 24 MB
  int* rp    = (int*)alloc(GTOT + 1);
  int* cnt   = (int*)alloc(GTOT + 1);
  float* INV1 = alloc(GTOT);
  float* INV2 = alloc(GTOT);
  float* ILB  = alloc((size_t)NBUc * 64);
  float* ILu  = alloc((size_t)B * 64);
  float* BLu  = alloc((size_t)B * 64);
  float* ILb2 = alloc((size_t)B * 128);
  float* BLb2 = alloc((size_t)B * 128);
  float* PN1  = alloc((size_t)B * 64);
  float* AN1  = alloc((size_t)B * 64);
  float* PN2  = alloc((size_t)B * 64);
  float* AN2  = alloc((size_t)B * 64);
  int* bCnt  = (int*)alloc(2049);
  int* bBase = (int*)alloc(2049);
  int* bCur  = (int*)alloc(2049);
  int* bsum  = (int*)alloc(256);
  (void)ws_size; (void)n_in; (void)out_size;

  // overlays into dead phases:
  unsigned short* F2b  = X;                        // spmm2 out overlays X (dead after spmm1)
  unsigned short* MACC = (unsigned short*)binned;  // 12.8MB; binned dead after csrfill
  float* S1 = ACC;                                 // ACC dead after gathers
  float* S2 = ACC + (size_t)B * B;

  // ---- unified bucketed binning + CSR (all 3 graphs) ----
  hipMemsetAsync(bCnt, 0, sizeof(int) * NBK, stream);
  k_bcount_all<<<1024, 256, 0, stream>>>(ui_u, ui_i, ub_u, ub_b, bi_b, E_ui, E_ub, E_bi, bCnt);
  k_scan2048<<<1, 512, 0, stream>>>(bCnt, NBK, bBase, bCur);
  k_bin_all<<<1024, 256, 0, stream>>>(ui_u, ui_i, ub_u, ub_b, bi_b, bi_i,
                                      E_ui, E_ub, E_bi, bCur, binned);
  hipMemsetAsync(cnt, 0, sizeof(int) * (GTOT + 1), stream);
  k_rowhist_all<<<NBK, 256, 0, stream>>>(binned, bBase, cnt);
  {
    int scan_n = GTOT + 1;
    int nb1 = (scan_n + 1023) / 1024;
    k_scan_block<<<nb1, 256, 0, stream>>>(cnt, scan_n, rp, bsum);
    k_scan_bsum<<<1, 256, 0, stream>>>(bsum, nb1);
    k_scan_add<<<(scan_n + 255) / 256, 256, 0, stream>>>(rp, scan_n, bsum);
  }
  k_csrfill_all<<<NBK, 256, 0, stream>>>(binned, bBase, rp, colv);

  // ---- propagate (UI + UB merged per layer) ----
  k_prescale_all<<<(int)(((long)GBI0 * 64 + 255) / 256), 256, 0, stream>>>(cnt, userF, bundF,
                                                                           itemF, X);
  k_spmm_g<<<(GBI0 + 3) / 4, 256, 0, stream>>>(rp, colv, X, M1, INV1, 0.5f, 1, GBI0);
  k_spmm_g<<<(GBI0 + 3) / 4, 256, 0, stream>>>(rp, colv, M1, F2b, INV2, 1.0f / 3.0f, 0, GBI0);
  k_acc_all<<<(int)(((long)(NILc + NBLc) * 64 + 255) / 256), 256, 0, stream>>>(
      userF, bundF, itemF, cnt, M1, F2b, INV1, INV2, ACC, MACC);
  k_agg_g<<<(NBUc + 3) / 4, 256, 0, stream>>>(rp, colv, MACC, ILB, NBUc);
  k_gather_all<<<(int)(((long)6 * B * 64 + 255) / 256), 256, 0, stream>>>(
      users, bundles, ACC, ILB, B, ILu, BLu, ILb2, BLb2);

  // ---- losses ----
  hipMemsetAsync(out, 0, 2 * sizeof(float), stream);
  k_bpr<<<(B + 3) / 4, 256, 0, stream>>>(ILu, ILb2, BLu, BLb2, B, out);
  k_normalize4<<<(4 * B + 3) / 4, 256, 0, stream>>>(ILu, BLu, ILb2, BLb2, PN1, AN1, PN2, AN2, B);
  dim3 gg((B + 127) / 128, (B + 127) / 128, 2);
  k_gemm_nt2<<<gg, 256, 0, stream>>>(PN1, AN1, PN2, AN2, S1, S2, B, 4.0f);  // 1/C_TEMP
  k_lse2<<<(2 * B + 3) / 4, 256, 0, stream>>>(S1, S2, B, 0.5f / (float)B, out);
}